// Round 4
// baseline (1842.755 us; speedup 1.0000x reference)
//
#include <hip/hip_runtime.h>
#include <hip/hip_bf16.h>
#include <cstdint>

#define DEV __device__ __forceinline__

typedef float    f32x4 __attribute__((ext_vector_type(4)));
typedef __bf16   bf8_t __attribute__((ext_vector_type(8)));
typedef unsigned short us8 __attribute__((ext_vector_type(8)));

DEV unsigned short bf(float f) {
  union { __hip_bfloat16 h; unsigned short u; } x;
  x.h = __float2bfloat16(f);
  return x.u;
}
DEV float fb(unsigned short u) {
  union { unsigned int u; float f; } x;
  x.u = (unsigned int)u << 16;
  return x.f;
}
DEV f32x4 mfma(bf8_t a, bf8_t b, f32x4 c) {
  return __builtin_amdgcn_mfma_f32_16x16x32_bf16(a, b, c, 0, 0, 0);
}

// weight arena offsets (bf16 elements) inside d_ws
#define OFF_QKV   0
#define OFF_OUT   49152
#define OFF_CONVP 65536
#define OFF_PW1   81920
#define OFF_TOK   98304
#define OFF_LPW   114688
#define OFF_FC1   131072
#define OFF_FC2   196608
#define OFF_PB    262144
#define W_TOTAL   266240

// ---------------- K0: convert weights (+pos_bias) to bf16 ----------------
__global__ __launch_bounds__(256)
void k_prep(const float* __restrict__ qkv_w, const float* __restrict__ out_w,
            const float* __restrict__ convp_w, const float* __restrict__ pw1_w,
            const float* __restrict__ tok_w, const float* __restrict__ lpw_w,
            const float* __restrict__ fc1_w, const float* __restrict__ fc2_w,
            const float* __restrict__ pos_b, unsigned short* __restrict__ Wb) {
  int i = blockIdx.x * 256 + threadIdx.x;
  float v;
  if      (i < OFF_OUT)   v = qkv_w[i - OFF_QKV];
  else if (i < OFF_CONVP) v = out_w[i - OFF_OUT];
  else if (i < OFF_PW1)   v = convp_w[i - OFF_CONVP];
  else if (i < OFF_TOK)   v = pw1_w[i - OFF_PW1];
  else if (i < OFF_LPW)   v = tok_w[i - OFF_TOK];
  else if (i < OFF_FC1)   v = lpw_w[i - OFF_LPW];
  else if (i < OFF_FC2)   v = fc1_w[i - OFF_FC1];
  else if (i < OFF_PB)    v = fc2_w[i - OFF_FC2];
  else                    v = pos_b[i - OFF_PB];
  Wb[i] = bf(v);
}

// ---------------- K1: fused remsa (one 8x8 window per block, 51KB LDS) ----------------
// x(regs,c-major) -> LN1 -> XN(bf16) -> qkv -> attn(all waves) -> out(acc) -> convp
// -> pw1 -> dw(tok) -> tok(acc) -> DT(bf16 transpose) -> y=x+DT (fp32 NCHW out)
// -> LN2 (c-major reduce) -> z -> lpw -> L1 (bf16 NHWC)
__global__ __launch_bounds__(256, 3)
void k_remsa(const float* __restrict__ x, const float* __restrict__ n1w,
             const float* __restrict__ n1b, const unsigned short* __restrict__ Wb,
             const float* __restrict__ qkv_b, const float* __restrict__ out_b,
             const float* __restrict__ convp_b, const float* __restrict__ pw1_b,
             const float* __restrict__ dw1_w, const float* __restrict__ dw1_b,
             const float* __restrict__ tok_b, const float* __restrict__ n2w,
             const float* __restrict__ n2b, float* __restrict__ yout,
             unsigned short* __restrict__ L1) {
  __shared__ __align__(16) char smem[52224];
  unsigned short* XN = (unsigned short*)smem;            // [64][136] bf16 xn -> t2 -> z
  unsigned short* AO = (unsigned short*)(smem + 17408);  // [64][136] bf16 ao -> t1 -> t3 ; LN2-RED overlay
  unsigned short* S  = (unsigned short*)(smem + 34816);  // LN1-RED / QK [16][392] / DT [128][68]
  float* SRED = (float*)(smem + 34816);
  float* ARED = (float*)(smem + 17408);

  const int t = threadIdx.x;
  const int l = t & 63, w = t >> 6;
  const int lr = l & 15, lhi = l >> 4;
  const int R0 = w * 16;
  const int p4 = (t & 15) * 4;        // 4 tokens p4..p4+3 (c-major phases)
  const int csub = t >> 4;            // c = csub + 16k
  const int pr = p4 >> 3, ps = p4 & 7;

  const int win = blockIdx.x;
  const int b = win >> 10, rem = win & 1023, hb = rem >> 5, wb = rem & 31;
  const float* xb = x + (size_t)b * 8388608 + (size_t)(hb * 8) * 256 + wb * 8;
  float*       yb = yout + (size_t)b * 8388608 + (size_t)(hb * 8) * 256 + wb * 8;

  const unsigned short* Wq = Wb + OFF_QKV;
  const unsigned short* Wo = Wb + OFF_OUT;
  const unsigned short* Wc = Wb + OFF_CONVP;
  const unsigned short* Wp = Wb + OFF_PW1;
  const unsigned short* Wt = Wb + OFF_TOK;
  const unsigned short* Wl = Wb + OFF_LPW;
  const unsigned short* PB = Wb + OFF_PB;

  // ---- load x (c-major, kept in regs for the whole kernel) ----
  float4 xv[8];
#pragma unroll
  for (int k = 0; k < 8; k++) {
    int c = csub + 16 * k;
    xv[k] = *(const float4*)&xb[(size_t)c * 65536 + pr * 256 + ps];
  }
  // ---- LN1 stats ----
  float s1[4] = {0.f, 0.f, 0.f, 0.f}, q1[4] = {0.f, 0.f, 0.f, 0.f};
#pragma unroll
  for (int k = 0; k < 8; k++) {
    s1[0] += xv[k].x; q1[0] += xv[k].x * xv[k].x;
    s1[1] += xv[k].y; q1[1] += xv[k].y * xv[k].y;
    s1[2] += xv[k].z; q1[2] += xv[k].z * xv[k].z;
    s1[3] += xv[k].w; q1[3] += xv[k].w * xv[k].w;
  }
#pragma unroll
  for (int m = 16; m <= 32; m <<= 1)
#pragma unroll
    for (int i = 0; i < 4; i++) {
      s1[i] += __shfl_xor(s1[i], m, 64);
      q1[i] += __shfl_xor(q1[i], m, 64);
    }
  if (lhi == 0)
#pragma unroll
    for (int i = 0; i < 4; i++) {
      SRED[w * 128 + (p4 + i) * 2]     = s1[i];
      SRED[w * 128 + (p4 + i) * 2 + 1] = q1[i];
    }
  __syncthreads();
  float mu1[4], rs1[4];
#pragma unroll
  for (int i = 0; i < 4; i++) {
    float ss = 0.f, qq = 0.f;
#pragma unroll
    for (int w2 = 0; w2 < 4; w2++) {
      ss += SRED[w2 * 128 + (p4 + i) * 2];
      qq += SRED[w2 * 128 + (p4 + i) * 2 + 1];
    }
    mu1[i] = ss * 0.0078125f;
    float var = qq * 0.0078125f - mu1[i] * mu1[i];
    rs1[i] = rsqrtf(var + 1e-5f);
  }
  // ---- normalize -> XN bf16 ----
#pragma unroll
  for (int k = 0; k < 8; k++) {
    int c = csub + 16 * k;
    float nw = n1w[c], nb = n1b[c];
    XN[(p4 + 0) * 136 + c] = bf((xv[k].x - mu1[0]) * rs1[0] * nw + nb);
    XN[(p4 + 1) * 136 + c] = bf((xv[k].y - mu1[1]) * rs1[1] * nw + nb);
    XN[(p4 + 2) * 136 + c] = bf((xv[k].z - mu1[2]) * rs1[2] * nw + nb);
    XN[(p4 + 3) * 136 + c] = bf((xv[k].w - mu1[3]) * rs1[3] * nw + nb);
  }
  __syncthreads();

  // ---- qkv GEMM + attention (all waves), 4 tiles of 16 tokens ----
  for (int tt = 0; tt < 4; tt++) {
    {
      bf8_t af[4];
#pragma unroll
      for (int kk = 0; kk < 4; kk++)
        af[kk] = *(const bf8_t*)&XN[(tt * 16 + lr) * 136 + kk * 32 + lhi * 8];
#pragma unroll
      for (int j = 0; j < 6; j++) {
        int o0 = w * 96 + j * 16;
        f32x4 acc = {0.f, 0.f, 0.f, 0.f};
#pragma unroll
        for (int kk = 0; kk < 4; kk++)
          acc = mfma(af[kk], *(const bf8_t*)&Wq[(size_t)(o0 + lr) * 128 + kk * 32 + lhi * 8], acc);
        float bias = qkv_b[o0 + lr];
#pragma unroll
        for (int reg = 0; reg < 4; reg++)
          S[(lhi * 4 + reg) * 392 + o0 + lr] = bf(acc[reg] + bias);
      }
    }
    __syncthreads();
    {
      // 256 threads over 128 items: pair (t, t+128) shares an item; each half
      // computes all 8 scores (redundant) but only 8 of 16 output dims.
      int half = t >> 7, lt = (t >> 3) & 15, hh = t & 7, n = tt * 16 + lt;
      const unsigned short* row = &S[lt * 392];
      float qv[16];
      us8 u0 = *(const us8*)&row[hh * 48], u1 = *(const us8*)&row[hh * 48 + 8];
#pragma unroll
      for (int d = 0; d < 8; d++) { qv[d] = fb(u0[d]); qv[8 + d] = fb(u1[d]); }
      us8 pb = *(const us8*)&PB[n * 64 + hh * 8];
      float sc[8], mx = -1e30f;
#pragma unroll
      for (int g = 0; g < 8; g++) {
        us8 k0 = *(const us8*)&row[g * 48 + 16], k1 = *(const us8*)&row[g * 48 + 24];
        float s = 0.f;
#pragma unroll
        for (int d = 0; d < 8; d++) s += qv[d] * fb(k0[d]) + qv[8 + d] * fb(k1[d]);
        s = s * 0.25f + fb(pb[g]);
        sc[g] = s; mx = fmaxf(mx, s);
      }
      float den = 0.f;
#pragma unroll
      for (int g = 0; g < 8; g++) { sc[g] = __expf(sc[g] - mx); den += sc[g]; }
      float inv = 1.f / den;
      float ov[8];
#pragma unroll
      for (int d = 0; d < 8; d++) ov[d] = 0.f;
#pragma unroll
      for (int g = 0; g < 8; g++) {
        us8 vv = *(const us8*)&row[g * 48 + 32 + half * 8];
        float sg = sc[g];
#pragma unroll
        for (int d = 0; d < 8; d++) ov[d] += sg * fb(vv[d]);
      }
      us8 op;
#pragma unroll
      for (int d = 0; d < 8; d++) op[d] = bf(ov[d] * inv);
      *(us8*)&AO[n * 136 + hh * 16 + half * 8] = op;
    }
    __syncthreads();
  }

  // ---- out-proj GEMM -> acc1 (wave-local rows from here on) ----
  f32x4 acc1[8];
#pragma unroll
  for (int j = 0; j < 8; j++) acc1[j] = (f32x4){0.f, 0.f, 0.f, 0.f};
  {
    bf8_t af[4];
#pragma unroll
    for (int kk = 0; kk < 4; kk++)
      af[kk] = *(const bf8_t*)&AO[(R0 + lr) * 136 + kk * 32 + lhi * 8];
#pragma unroll
    for (int j = 0; j < 8; j++)
#pragma unroll
      for (int kk = 0; kk < 4; kk++)
        acc1[j] = mfma(af[kk], *(const bf8_t*)&Wo[(size_t)(j * 16 + lr) * 128 + kk * 32 + lhi * 8], acc1[j]);
  }
  // ---- convp GEMM (XN) -> t1 (own rows of AO) ----
  {
    f32x4 acc2[8];
#pragma unroll
    for (int j = 0; j < 8; j++) acc2[j] = (f32x4){0.f, 0.f, 0.f, 0.f};
    bf8_t af[4];
#pragma unroll
    for (int kk = 0; kk < 4; kk++)
      af[kk] = *(const bf8_t*)&XN[(R0 + lr) * 136 + kk * 32 + lhi * 8];
#pragma unroll
    for (int j = 0; j < 8; j++)
#pragma unroll
      for (int kk = 0; kk < 4; kk++)
        acc2[j] = mfma(af[kk], *(const bf8_t*)&Wc[(size_t)(j * 16 + lr) * 128 + kk * 32 + lhi * 8], acc2[j]);
#pragma unroll
    for (int j = 0; j < 8; j++) {
      float bias = convp_b[j * 16 + lr];
#pragma unroll
      for (int reg = 0; reg < 4; reg++)
        AO[(R0 + lhi * 4 + reg) * 136 + j * 16 + lr] = bf(acc2[j][reg] + bias);
    }
  }
  // ---- pw1 GEMM (t1, own rows) -> t2 (own rows of XN) ----
  {
    f32x4 acc2[8];
#pragma unroll
    for (int j = 0; j < 8; j++) acc2[j] = (f32x4){0.f, 0.f, 0.f, 0.f};
    bf8_t af[4];
#pragma unroll
    for (int kk = 0; kk < 4; kk++)
      af[kk] = *(const bf8_t*)&AO[(R0 + lr) * 136 + kk * 32 + lhi * 8];
#pragma unroll
    for (int j = 0; j < 8; j++)
#pragma unroll
      for (int kk = 0; kk < 4; kk++)
        acc2[j] = mfma(af[kk], *(const bf8_t*)&Wp[(size_t)(j * 16 + lr) * 128 + kk * 32 + lhi * 8], acc2[j]);
#pragma unroll
    for (int j = 0; j < 8; j++) {
      float bias = pw1_b[j * 16 + lr];
#pragma unroll
      for (int reg = 0; reg < 4; reg++)
        XN[(R0 + lhi * 4 + reg) * 136 + j * 16 + lr] = bf(acc2[j][reg] + bias);
    }
  }
  __syncthreads();   // t2 complete (dw reads neighbor rows)

  // ---- depthwise token conv: t2 -> t3 (own rows of AO) ----
  {
    float dwc[2][4];
#pragma unroll
    for (int h2 = 0; h2 < 2; h2++) {
      int c = l + 64 * h2;
      dwc[h2][0] = dw1_w[c * 3]; dwc[h2][1] = dw1_w[c * 3 + 1];
      dwc[h2][2] = dw1_w[c * 3 + 2]; dwc[h2][3] = dw1_b[c];
    }
#pragma unroll
    for (int k2 = 0; k2 < 32; k2++) {
      int n = R0 + (k2 >> 1), h2 = k2 & 1, c = l + 64 * h2;
      float v = dwc[h2][3] + dwc[h2][1] * fb(XN[n * 136 + c]);
      if (n > 0)  v += dwc[h2][0] * fb(XN[(n - 1) * 136 + c]);
      if (n < 63) v += dwc[h2][2] * fb(XN[(n + 1) * 136 + c]);
      AO[n * 136 + c] = bf(v);
    }
  }
  // ---- tok GEMM (t3, own rows) chained into acc1 ----
  {
    bf8_t af[4];
#pragma unroll
    for (int kk = 0; kk < 4; kk++)
      af[kk] = *(const bf8_t*)&AO[(R0 + lr) * 136 + kk * 32 + lhi * 8];
#pragma unroll
    for (int j = 0; j < 8; j++)
#pragma unroll
      for (int kk = 0; kk < 4; kk++)
        acc1[j] = mfma(af[kk], *(const bf8_t*)&Wt[(size_t)(j * 16 + lr) * 128 + kk * 32 + lhi * 8], acc1[j]);
  }
  // ---- Delta transpose (bf16) into S ----
  unsigned short* DT = S;   // [128][68]
#pragma unroll
  for (int j = 0; j < 8; j++) {
    int col = j * 16 + lr;
    float bsum = out_b[col] + tok_b[col];
#pragma unroll
    for (int reg = 0; reg < 4; reg++)
      DT[col * 68 + R0 + lhi * 4 + reg] = bf(acc1[j][reg] + bsum);
  }
  __syncthreads();

  // ---- c-major epilogue: y = x + Delta; write yout; LN2 partials ----
  float4 yv[8];
  float s2[4] = {0.f, 0.f, 0.f, 0.f}, q2[4] = {0.f, 0.f, 0.f, 0.f};
#pragma unroll
  for (int k = 0; k < 8; k++) {
    int c = csub + 16 * k;
    uint2 d2 = *(const uint2*)&DT[c * 68 + p4];
    float4 v;
    v.x = xv[k].x + fb((unsigned short)(d2.x & 0xffff));
    v.y = xv[k].y + fb((unsigned short)(d2.x >> 16));
    v.z = xv[k].z + fb((unsigned short)(d2.y & 0xffff));
    v.w = xv[k].w + fb((unsigned short)(d2.y >> 16));
    yv[k] = v;
    *(float4*)&yb[(size_t)c * 65536 + pr * 256 + ps] = v;
    s2[0] += v.x; q2[0] += v.x * v.x;
    s2[1] += v.y; q2[1] += v.y * v.y;
    s2[2] += v.z; q2[2] += v.z * v.z;
    s2[3] += v.w; q2[3] += v.w * v.w;
  }
#pragma unroll
  for (int m = 16; m <= 32; m <<= 1)
#pragma unroll
    for (int i = 0; i < 4; i++) {
      s2[i] += __shfl_xor(s2[i], m, 64);
      q2[i] += __shfl_xor(q2[i], m, 64);
    }
  if (lhi == 0)
#pragma unroll
    for (int i = 0; i < 4; i++) {
      ARED[w * 128 + (p4 + i) * 2]     = s2[i];
      ARED[w * 128 + (p4 + i) * 2 + 1] = q2[i];
    }
  __syncthreads();
  float mu2[4], rs2[4];
#pragma unroll
  for (int i = 0; i < 4; i++) {
    float ss = 0.f, qq = 0.f;
#pragma unroll
    for (int w2 = 0; w2 < 4; w2++) {
      ss += ARED[w2 * 128 + (p4 + i) * 2];
      qq += ARED[w2 * 128 + (p4 + i) * 2 + 1];
    }
    mu2[i] = ss * 0.0078125f;
    float var = qq * 0.0078125f - mu2[i] * mu2[i];
    rs2[i] = rsqrtf(var + 1e-5f);
  }
  // ---- z -> XN ----
#pragma unroll
  for (int k = 0; k < 8; k++) {
    int c = csub + 16 * k;
    float nw = n2w[c], nb = n2b[c];
    XN[(p4 + 0) * 136 + c] = bf((yv[k].x - mu2[0]) * rs2[0] * nw + nb);
    XN[(p4 + 1) * 136 + c] = bf((yv[k].y - mu2[1]) * rs2[1] * nw + nb);
    XN[(p4 + 2) * 136 + c] = bf((yv[k].z - mu2[2]) * rs2[2] * nw + nb);
    XN[(p4 + 3) * 136 + c] = bf((yv[k].w - mu2[3]) * rs2[3] * nw + nb);
  }
  __syncthreads();
  // ---- lpw GEMM -> L1 (bf16 NHWC) ----
  {
    bf8_t af[4];
#pragma unroll
    for (int kk = 0; kk < 4; kk++)
      af[kk] = *(const bf8_t*)&XN[(R0 + lr) * 136 + kk * 32 + lhi * 8];
#pragma unroll
    for (int j = 0; j < 8; j++) {
      f32x4 acc = {0.f, 0.f, 0.f, 0.f};
#pragma unroll
      for (int kk = 0; kk < 4; kk++)
        acc = mfma(af[kk], *(const bf8_t*)&Wl[(size_t)(j * 16 + lr) * 128 + kk * 32 + lhi * 8], acc);
#pragma unroll
      for (int reg = 0; reg < 4; reg++) {
        int rowp = R0 + lhi * 4 + reg;
        size_t pix = ((size_t)b * 256 + hb * 8 + (rowp >> 3)) * 256 + wb * 8 + (rowp & 7);
        L1[pix * 128 + j * 16 + lr] = bf(acc[reg]);
      }
    }
  }
}

// ---------------- K2: 3x3 depthwise conv (bf16 NHWC, 8 ch/thread) ----------------
__global__ __launch_bounds__(256)
void k_dw3(const unsigned short* __restrict__ L1, const float* __restrict__ dwW,
           const float* __restrict__ dwB, unsigned short* __restrict__ L2) {
  size_t tid = (size_t)blockIdx.x * 256 + threadIdx.x;
  int c8 = (int)(tid & 15) * 8;
  size_t pixi = tid >> 4;
  int b = (int)(pixi >> 16), rr = (int)(pixi & 65535), h = rr >> 8, w = rr & 255;
  float acc[8];
#pragma unroll
  for (int e = 0; e < 8; e++) acc[e] = dwB[c8 + e];
#pragma unroll
  for (int i = 0; i < 3; i++) {
    int h2 = h + i - 1;
    if (h2 < 0 || h2 > 255) continue;
#pragma unroll
    for (int j = 0; j < 3; j++) {
      int w2 = w + j - 1;
      if (w2 < 0 || w2 > 255) continue;
      us8 raw = *(const us8*)&L1[(((size_t)b * 256 + h2) * 256 + w2) * 128 + c8];
#pragma unroll
      for (int e = 0; e < 8; e++)
        acc[e] += fb(raw[e]) * dwW[(c8 + e) * 9 + i * 3 + j];
    }
  }
  us8 o;
#pragma unroll
  for (int e = 0; e < 8; e++) o[e] = bf(acc[e]);
  *(us8*)&L2[pixi * 128 + c8] = o;
}

// ---------------- K3: fc1 + GELU + fc2 + residual (2 barriers, 51KB LDS) ----------------
__global__ __launch_bounds__(256, 3)
void k_ffn(const unsigned short* __restrict__ L2b, const unsigned short* __restrict__ Wb,
           const float* __restrict__ fc1_b, const float* __restrict__ fc2_b,
           float* __restrict__ out) {
  __shared__ __align__(16) char smem[52224];
  unsigned short* ZT = (unsigned short*)smem;            // [64][136]
  unsigned short* HS = (unsigned short*)(smem + 17408);  // [64][136]
  unsigned short* DT = (unsigned short*)(smem + 34816);  // [128][68]

  const int t = threadIdx.x;
  const int l = t & 63, w = t >> 6;
  const int lr = l & 15, lhi = l >> 4;
  const int R0 = w * 16;

  size_t pix0 = (size_t)blockIdx.x * 64;
  const int b = (int)(pix0 >> 16), h = (int)((pix0 >> 8) & 255), w0c = (int)(pix0 & 255);

  const unsigned short* W1 = Wb + OFF_FC1;
  const unsigned short* W2 = Wb + OFF_FC2;

  for (int i = t; i < 1024; i += 256) {
    int n = i >> 4, c8 = (i & 15) * 8;
    *(us8*)&ZT[n * 136 + c8] = *(const us8*)&L2b[(pix0 + n) * 128 + c8];
  }
  __syncthreads();

  bf8_t a1[4];
#pragma unroll
  for (int kk = 0; kk < 4; kk++)
    a1[kk] = *(const bf8_t*)&ZT[(R0 + lr) * 136 + kk * 32 + lhi * 8];

  f32x4 facc[8];
#pragma unroll
  for (int j = 0; j < 8; j++) facc[j] = (f32x4){0.f, 0.f, 0.f, 0.f};

  for (int chunk = 0; chunk < 4; chunk++) {
    int hc = chunk * 128;
#pragma unroll
    for (int j = 0; j < 8; j++) {
      f32x4 ha = {0.f, 0.f, 0.f, 0.f};
#pragma unroll
      for (int kk = 0; kk < 4; kk++)
        ha = mfma(a1[kk], *(const bf8_t*)&W1[(size_t)(hc + j * 16 + lr) * 128 + kk * 32 + lhi * 8], ha);
      float bias = fc1_b[hc + j * 16 + lr];
#pragma unroll
      for (int reg = 0; reg < 4; reg++) {
        float v = ha[reg] + bias;
        HS[(R0 + lhi * 4 + reg) * 136 + j * 16 + lr] = bf(0.5f * v * (1.f + erff(v * 0.70710678118f)));
      }
    }
    bf8_t a2[4];   // own rows: wave-local, no barrier needed
#pragma unroll
    for (int kk = 0; kk < 4; kk++)
      a2[kk] = *(const bf8_t*)&HS[(R0 + lr) * 136 + kk * 32 + lhi * 8];
#pragma unroll
    for (int j = 0; j < 8; j++)
#pragma unroll
      for (int kk = 0; kk < 4; kk++)
        facc[j] = mfma(a2[kk], *(const bf8_t*)&W2[(size_t)(j * 16 + lr) * 512 + hc + kk * 32 + lhi * 8], facc[j]);
  }
#pragma unroll
  for (int j = 0; j < 8; j++) {
    int col = j * 16 + lr;
    float bias = fc2_b[col];
#pragma unroll
    for (int reg = 0; reg < 4; reg++)
      DT[col * 68 + R0 + lhi * 4 + reg] = bf(facc[j][reg] + bias);
  }
  __syncthreads();
  int p4 = (t & 15) * 4, csub = t >> 4;
#pragma unroll
  for (int k = 0; k < 8; k++) {
    int c = csub + 16 * k;
    float* po = &out[((size_t)(b * 128 + c)) * 65536 + (size_t)h * 256 + w0c + p4];
    float4 v = *(const float4*)po;
    uint2 d2 = *(const uint2*)&DT[c * 68 + p4];
    v.x += fb((unsigned short)(d2.x & 0xffff));
    v.y += fb((unsigned short)(d2.x >> 16));
    v.z += fb((unsigned short)(d2.y & 0xffff));
    v.w += fb((unsigned short)(d2.y >> 16));
    *(float4*)po = v;
  }
}

// ---------------- launch ----------------
extern "C" void kernel_launch(void* const* d_in, const int* in_sizes, int n_in,
                              void* d_out, int out_size, void* d_ws, size_t ws_size,
                              hipStream_t stream) {
  const float* x       = (const float*)d_in[0];
  const float* norm1_w = (const float*)d_in[1];
  const float* norm1_b = (const float*)d_in[2];
  const float* qkv_w   = (const float*)d_in[3];
  const float* qkv_b   = (const float*)d_in[4];
  const float* pos_b   = (const float*)d_in[5];
  const float* out_w   = (const float*)d_in[6];
  const float* out_b   = (const float*)d_in[7];
  const float* convp_w = (const float*)d_in[8];
  const float* convp_b = (const float*)d_in[9];
  const float* pw1_w   = (const float*)d_in[10];
  const float* pw1_b   = (const float*)d_in[11];
  const float* dw1_w   = (const float*)d_in[12];
  const float* dw1_b   = (const float*)d_in[13];
  const float* tok_w   = (const float*)d_in[14];
  const float* tok_b   = (const float*)d_in[15];
  const float* norm2_w = (const float*)d_in[16];
  const float* norm2_b = (const float*)d_in[17];
  const float* lpw_w   = (const float*)d_in[18];
  const float* ldw_w   = (const float*)d_in[19];
  const float* ldw_b   = (const float*)d_in[20];
  const float* fc1_w   = (const float*)d_in[21];
  const float* fc1_b   = (const float*)d_in[22];
  const float* fc2_w   = (const float*)d_in[23];
  const float* fc2_b   = (const float*)d_in[24];
  float* out = (float*)d_out;

  unsigned short* Wbf = (unsigned short*)d_ws;                                 // 532 KB arena
  unsigned short* L1  = (unsigned short*)((char*)d_ws + (1u << 20));           // 64 MB bf16
  unsigned short* L2  = (unsigned short*)((char*)d_ws + (1u << 20) + (64u << 20));

  k_prep<<<1040, 256, 0, stream>>>(qkv_w, out_w, convp_w, pw1_w, tok_w, lpw_w,
                                   fc1_w, fc2_w, pos_b, Wbf);
  k_remsa<<<4096, 256, 0, stream>>>(x, norm1_w, norm1_b, Wbf, qkv_b, out_b,
                                    convp_b, pw1_b, dw1_w, dw1_b, tok_b,
                                    norm2_w, norm2_b, out, L1);
  k_dw3<<<16384, 256, 0, stream>>>(L1, ldw_w, ldw_b, L2);
  k_ffn<<<4096, 256, 0, stream>>>(L2, Wbf, fc1_b, fc2_b, out);
}

// Round 5
// 1719.823 us; speedup vs baseline: 1.0715x; 1.0715x over previous
//
#include <hip/hip_runtime.h>
#include <hip/hip_bf16.h>
#include <cstdint>

#define DEV __device__ __forceinline__

typedef float    f32x4 __attribute__((ext_vector_type(4)));
typedef __bf16   bf8_t __attribute__((ext_vector_type(8)));
typedef unsigned short us8 __attribute__((ext_vector_type(8)));

DEV unsigned short bf(float f) {
  union { __hip_bfloat16 h; unsigned short u; } x;
  x.h = __float2bfloat16(f);
  return x.u;
}
DEV float fb(unsigned short u) {
  union { unsigned int u; float f; } x;
  x.u = (unsigned int)u << 16;
  return x.f;
}
DEV f32x4 mfma(bf8_t a, bf8_t b, f32x4 c) {
  return __builtin_amdgcn_mfma_f32_16x16x32_bf16(a, b, c, 0, 0, 0);
}

// weight arena offsets (bf16 elements) inside d_ws
#define OFF_QKV   0
#define OFF_OUT   49152
#define OFF_CONVP 65536
#define OFF_PW1   81920
#define OFF_TOK   98304
#define OFF_LPW   114688
#define OFF_FC1   131072
#define OFF_FC2   196608
#define OFF_PB    262144
#define W_TOTAL   266240

// ---------------- K0: convert weights (+pos_bias) to bf16 ----------------
__global__ __launch_bounds__(256)
void k_prep(const float* __restrict__ qkv_w, const float* __restrict__ out_w,
            const float* __restrict__ convp_w, const float* __restrict__ pw1_w,
            const float* __restrict__ tok_w, const float* __restrict__ lpw_w,
            const float* __restrict__ fc1_w, const float* __restrict__ fc2_w,
            const float* __restrict__ pos_b, unsigned short* __restrict__ Wb) {
  int i = blockIdx.x * 256 + threadIdx.x;
  float v;
  if      (i < OFF_OUT)   v = qkv_w[i - OFF_QKV];
  else if (i < OFF_CONVP) v = out_w[i - OFF_OUT];
  else if (i < OFF_PW1)   v = convp_w[i - OFF_CONVP];
  else if (i < OFF_TOK)   v = pw1_w[i - OFF_PW1];
  else if (i < OFF_LPW)   v = tok_w[i - OFF_TOK];
  else if (i < OFF_FC1)   v = lpw_w[i - OFF_LPW];
  else if (i < OFF_FC2)   v = fc1_w[i - OFF_FC1];
  else if (i < OFF_PB)    v = fc2_w[i - OFF_FC2];
  else                    v = pos_b[i - OFF_PB];
  Wb[i] = bf(v);
}

// ---------------- K1: fused remsa (one 8x8 window per block, 51KB LDS) ----------------
// launch_bounds (256,2): do NOT force >2 waves/EU — (256,3) made the compiler
// squeeze to 84 VGPR and spill ~520MB/dispatch to scratch (round-4 counters).
// LDS 52224B still admits 3 blocks/CU when VGPR <= 168.
__global__ __launch_bounds__(256, 2)
void k_remsa(const float* __restrict__ x, const float* __restrict__ n1w,
             const float* __restrict__ n1b, const unsigned short* __restrict__ Wb,
             const float* __restrict__ qkv_b, const float* __restrict__ out_b,
             const float* __restrict__ convp_b, const float* __restrict__ pw1_b,
             const float* __restrict__ dw1_w, const float* __restrict__ dw1_b,
             const float* __restrict__ tok_b, const float* __restrict__ n2w,
             const float* __restrict__ n2b, float* __restrict__ yout,
             unsigned short* __restrict__ L1) {
  __shared__ __align__(16) char smem[52224];
  unsigned short* XN = (unsigned short*)smem;            // [64][136] bf16 xn -> t2 -> z
  unsigned short* AO = (unsigned short*)(smem + 17408);  // [64][136] bf16 ao -> t1 -> t3 ; LN2-RED overlay
  unsigned short* S  = (unsigned short*)(smem + 34816);  // LN1-RED / QK [16][392] / DT [128][68]
  float* SRED = (float*)(smem + 34816);
  float* ARED = (float*)(smem + 17408);

  const int t = threadIdx.x;
  const int l = t & 63, w = t >> 6;
  const int lr = l & 15, lhi = l >> 4;
  const int R0 = w * 16;
  const int p4 = (t & 15) * 4;        // 4 tokens p4..p4+3 (c-major phases)
  const int csub = t >> 4;            // c = csub + 16k
  const int pr = p4 >> 3, ps = p4 & 7;

  // XCD-aware swizzle (bijective: 4096 % 8 == 0): each XCD gets a contiguous
  // range of windows so horizontally-adjacent windows (sharing 64B x/y lines)
  // hit the same L2.
  const int win = ((blockIdx.x & 7) << 9) | (blockIdx.x >> 3);
  const int b = win >> 10, rem = win & 1023, hb = rem >> 5, wb = rem & 31;
  const float* xb = x + (size_t)b * 8388608 + (size_t)(hb * 8) * 256 + wb * 8;
  float*       yb = yout + (size_t)b * 8388608 + (size_t)(hb * 8) * 256 + wb * 8;

  const unsigned short* Wq = Wb + OFF_QKV;
  const unsigned short* Wo = Wb + OFF_OUT;
  const unsigned short* Wc = Wb + OFF_CONVP;
  const unsigned short* Wp = Wb + OFF_PW1;
  const unsigned short* Wt = Wb + OFF_TOK;
  const unsigned short* Wl = Wb + OFF_LPW;
  const unsigned short* PB = Wb + OFF_PB;

  // ---- load x (c-major, kept in regs for the whole kernel) ----
  float4 xv[8];
#pragma unroll
  for (int k = 0; k < 8; k++) {
    int c = csub + 16 * k;
    xv[k] = *(const float4*)&xb[(size_t)c * 65536 + pr * 256 + ps];
  }
  // ---- LN1 stats ----
  float s1[4] = {0.f, 0.f, 0.f, 0.f}, q1[4] = {0.f, 0.f, 0.f, 0.f};
#pragma unroll
  for (int k = 0; k < 8; k++) {
    s1[0] += xv[k].x; q1[0] += xv[k].x * xv[k].x;
    s1[1] += xv[k].y; q1[1] += xv[k].y * xv[k].y;
    s1[2] += xv[k].z; q1[2] += xv[k].z * xv[k].z;
    s1[3] += xv[k].w; q1[3] += xv[k].w * xv[k].w;
  }
#pragma unroll
  for (int m = 16; m <= 32; m <<= 1)
#pragma unroll
    for (int i = 0; i < 4; i++) {
      s1[i] += __shfl_xor(s1[i], m, 64);
      q1[i] += __shfl_xor(q1[i], m, 64);
    }
  if (lhi == 0)
#pragma unroll
    for (int i = 0; i < 4; i++) {
      SRED[w * 128 + (p4 + i) * 2]     = s1[i];
      SRED[w * 128 + (p4 + i) * 2 + 1] = q1[i];
    }
  __syncthreads();
  float mu1[4], rs1[4];
#pragma unroll
  for (int i = 0; i < 4; i++) {
    float ss = 0.f, qq = 0.f;
#pragma unroll
    for (int w2 = 0; w2 < 4; w2++) {
      ss += SRED[w2 * 128 + (p4 + i) * 2];
      qq += SRED[w2 * 128 + (p4 + i) * 2 + 1];
    }
    mu1[i] = ss * 0.0078125f;
    float var = qq * 0.0078125f - mu1[i] * mu1[i];
    rs1[i] = rsqrtf(var + 1e-5f);
  }
  // ---- normalize -> XN bf16 ----
#pragma unroll
  for (int k = 0; k < 8; k++) {
    int c = csub + 16 * k;
    float nw = n1w[c], nb = n1b[c];
    XN[(p4 + 0) * 136 + c] = bf((xv[k].x - mu1[0]) * rs1[0] * nw + nb);
    XN[(p4 + 1) * 136 + c] = bf((xv[k].y - mu1[1]) * rs1[1] * nw + nb);
    XN[(p4 + 2) * 136 + c] = bf((xv[k].z - mu1[2]) * rs1[2] * nw + nb);
    XN[(p4 + 3) * 136 + c] = bf((xv[k].w - mu1[3]) * rs1[3] * nw + nb);
  }
  __syncthreads();

  // ---- qkv GEMM + attention (all waves), 4 tiles of 16 tokens ----
  for (int tt = 0; tt < 4; tt++) {
    {
      bf8_t af[4];
#pragma unroll
      for (int kk = 0; kk < 4; kk++)
        af[kk] = *(const bf8_t*)&XN[(tt * 16 + lr) * 136 + kk * 32 + lhi * 8];
#pragma unroll
      for (int j = 0; j < 6; j++) {
        int o0 = w * 96 + j * 16;
        f32x4 acc = {0.f, 0.f, 0.f, 0.f};
#pragma unroll
        for (int kk = 0; kk < 4; kk++)
          acc = mfma(af[kk], *(const bf8_t*)&Wq[(size_t)(o0 + lr) * 128 + kk * 32 + lhi * 8], acc);
        float bias = qkv_b[o0 + lr];
#pragma unroll
        for (int reg = 0; reg < 4; reg++)
          S[(lhi * 4 + reg) * 392 + o0 + lr] = bf(acc[reg] + bias);
      }
    }
    __syncthreads();
    {
      // 256 threads over 128 items: pair (t, t+128) shares an item; each half
      // computes all 8 scores (redundant) but only 8 of 16 output dims.
      int half = t >> 7, lt = (t >> 3) & 15, hh = t & 7, n = tt * 16 + lt;
      const unsigned short* row = &S[lt * 392];
      float qv[16];
      us8 u0 = *(const us8*)&row[hh * 48], u1 = *(const us8*)&row[hh * 48 + 8];
#pragma unroll
      for (int d = 0; d < 8; d++) { qv[d] = fb(u0[d]); qv[8 + d] = fb(u1[d]); }
      us8 pb = *(const us8*)&PB[n * 64 + hh * 8];
      float sc[8], mx = -1e30f;
#pragma unroll
      for (int g = 0; g < 8; g++) {
        us8 k0 = *(const us8*)&row[g * 48 + 16], k1 = *(const us8*)&row[g * 48 + 24];
        float s = 0.f;
#pragma unroll
        for (int d = 0; d < 8; d++) s += qv[d] * fb(k0[d]) + qv[8 + d] * fb(k1[d]);
        s = s * 0.25f + fb(pb[g]);
        sc[g] = s; mx = fmaxf(mx, s);
      }
      float den = 0.f;
#pragma unroll
      for (int g = 0; g < 8; g++) { sc[g] = __expf(sc[g] - mx); den += sc[g]; }
      float inv = 1.f / den;
      float ov[8];
#pragma unroll
      for (int d = 0; d < 8; d++) ov[d] = 0.f;
#pragma unroll
      for (int g = 0; g < 8; g++) {
        us8 vv = *(const us8*)&row[g * 48 + 32 + half * 8];
        float sg = sc[g];
#pragma unroll
        for (int d = 0; d < 8; d++) ov[d] += sg * fb(vv[d]);
      }
      us8 op;
#pragma unroll
      for (int d = 0; d < 8; d++) op[d] = bf(ov[d] * inv);
      *(us8*)&AO[n * 136 + hh * 16 + half * 8] = op;
    }
    __syncthreads();
  }

  // ---- out-proj GEMM -> acc1 (wave-local rows from here on) ----
  f32x4 acc1[8];
#pragma unroll
  for (int j = 0; j < 8; j++) acc1[j] = (f32x4){0.f, 0.f, 0.f, 0.f};
  {
    bf8_t af[4];
#pragma unroll
    for (int kk = 0; kk < 4; kk++)
      af[kk] = *(const bf8_t*)&AO[(R0 + lr) * 136 + kk * 32 + lhi * 8];
#pragma unroll
    for (int j = 0; j < 8; j++)
#pragma unroll
      for (int kk = 0; kk < 4; kk++)
        acc1[j] = mfma(af[kk], *(const bf8_t*)&Wo[(size_t)(j * 16 + lr) * 128 + kk * 32 + lhi * 8], acc1[j]);
  }
  // ---- convp GEMM (XN) -> t1 (own rows of AO) ----
  {
    f32x4 acc2[8];
#pragma unroll
    for (int j = 0; j < 8; j++) acc2[j] = (f32x4){0.f, 0.f, 0.f, 0.f};
    bf8_t af[4];
#pragma unroll
    for (int kk = 0; kk < 4; kk++)
      af[kk] = *(const bf8_t*)&XN[(R0 + lr) * 136 + kk * 32 + lhi * 8];
#pragma unroll
    for (int j = 0; j < 8; j++)
#pragma unroll
      for (int kk = 0; kk < 4; kk++)
        acc2[j] = mfma(af[kk], *(const bf8_t*)&Wc[(size_t)(j * 16 + lr) * 128 + kk * 32 + lhi * 8], acc2[j]);
#pragma unroll
    for (int j = 0; j < 8; j++) {
      float bias = convp_b[j * 16 + lr];
#pragma unroll
      for (int reg = 0; reg < 4; reg++)
        AO[(R0 + lhi * 4 + reg) * 136 + j * 16 + lr] = bf(acc2[j][reg] + bias);
    }
  }
  // ---- pw1 GEMM (t1, own rows) -> t2 (own rows of XN) ----
  {
    f32x4 acc2[8];
#pragma unroll
    for (int j = 0; j < 8; j++) acc2[j] = (f32x4){0.f, 0.f, 0.f, 0.f};
    bf8_t af[4];
#pragma unroll
    for (int kk = 0; kk < 4; kk++)
      af[kk] = *(const bf8_t*)&AO[(R0 + lr) * 136 + kk * 32 + lhi * 8];
#pragma unroll
    for (int j = 0; j < 8; j++)
#pragma unroll
      for (int kk = 0; kk < 4; kk++)
        acc2[j] = mfma(af[kk], *(const bf8_t*)&Wp[(size_t)(j * 16 + lr) * 128 + kk * 32 + lhi * 8], acc2[j]);
#pragma unroll
    for (int j = 0; j < 8; j++) {
      float bias = pw1_b[j * 16 + lr];
#pragma unroll
      for (int reg = 0; reg < 4; reg++)
        XN[(R0 + lhi * 4 + reg) * 136 + j * 16 + lr] = bf(acc2[j][reg] + bias);
    }
  }
  __syncthreads();   // t2 complete (dw reads neighbor rows)

  // ---- depthwise token conv: t2 -> t3 (own rows of AO) ----
  {
    float dwc[2][4];
#pragma unroll
    for (int h2 = 0; h2 < 2; h2++) {
      int c = l + 64 * h2;
      dwc[h2][0] = dw1_w[c * 3]; dwc[h2][1] = dw1_w[c * 3 + 1];
      dwc[h2][2] = dw1_w[c * 3 + 2]; dwc[h2][3] = dw1_b[c];
    }
#pragma unroll
    for (int k2 = 0; k2 < 32; k2++) {
      int n = R0 + (k2 >> 1), h2 = k2 & 1, c = l + 64 * h2;
      float v = dwc[h2][3] + dwc[h2][1] * fb(XN[n * 136 + c]);
      if (n > 0)  v += dwc[h2][0] * fb(XN[(n - 1) * 136 + c]);
      if (n < 63) v += dwc[h2][2] * fb(XN[(n + 1) * 136 + c]);
      AO[n * 136 + c] = bf(v);
    }
  }
  // ---- tok GEMM (t3, own rows) chained into acc1 ----
  {
    bf8_t af[4];
#pragma unroll
    for (int kk = 0; kk < 4; kk++)
      af[kk] = *(const bf8_t*)&AO[(R0 + lr) * 136 + kk * 32 + lhi * 8];
#pragma unroll
    for (int j = 0; j < 8; j++)
#pragma unroll
      for (int kk = 0; kk < 4; kk++)
        acc1[j] = mfma(af[kk], *(const bf8_t*)&Wt[(size_t)(j * 16 + lr) * 128 + kk * 32 + lhi * 8], acc1[j]);
  }
  // ---- Delta transpose (bf16) into S ----
  unsigned short* DT = S;   // [128][68]
#pragma unroll
  for (int j = 0; j < 8; j++) {
    int col = j * 16 + lr;
    float bsum = out_b[col] + tok_b[col];
#pragma unroll
    for (int reg = 0; reg < 4; reg++)
      DT[col * 68 + R0 + lhi * 4 + reg] = bf(acc1[j][reg] + bsum);
  }
  __syncthreads();

  // ---- c-major epilogue: y = x + Delta; write yout; LN2 partials ----
  float4 yv[8];
  float s2[4] = {0.f, 0.f, 0.f, 0.f}, q2[4] = {0.f, 0.f, 0.f, 0.f};
#pragma unroll
  for (int k = 0; k < 8; k++) {
    int c = csub + 16 * k;
    uint2 d2 = *(const uint2*)&DT[c * 68 + p4];
    float4 v;
    v.x = xv[k].x + fb((unsigned short)(d2.x & 0xffff));
    v.y = xv[k].y + fb((unsigned short)(d2.x >> 16));
    v.z = xv[k].z + fb((unsigned short)(d2.y & 0xffff));
    v.w = xv[k].w + fb((unsigned short)(d2.y >> 16));
    yv[k] = v;
    *(float4*)&yb[(size_t)c * 65536 + pr * 256 + ps] = v;
    s2[0] += v.x; q2[0] += v.x * v.x;
    s2[1] += v.y; q2[1] += v.y * v.y;
    s2[2] += v.z; q2[2] += v.z * v.z;
    s2[3] += v.w; q2[3] += v.w * v.w;
  }
#pragma unroll
  for (int m = 16; m <= 32; m <<= 1)
#pragma unroll
    for (int i = 0; i < 4; i++) {
      s2[i] += __shfl_xor(s2[i], m, 64);
      q2[i] += __shfl_xor(q2[i], m, 64);
    }
  if (lhi == 0)
#pragma unroll
    for (int i = 0; i < 4; i++) {
      ARED[w * 128 + (p4 + i) * 2]     = s2[i];
      ARED[w * 128 + (p4 + i) * 2 + 1] = q2[i];
    }
  __syncthreads();
  float mu2[4], rs2[4];
#pragma unroll
  for (int i = 0; i < 4; i++) {
    float ss = 0.f, qq = 0.f;
#pragma unroll
    for (int w2 = 0; w2 < 4; w2++) {
      ss += ARED[w2 * 128 + (p4 + i) * 2];
      qq += ARED[w2 * 128 + (p4 + i) * 2 + 1];
    }
    mu2[i] = ss * 0.0078125f;
    float var = qq * 0.0078125f - mu2[i] * mu2[i];
    rs2[i] = rsqrtf(var + 1e-5f);
  }
  // ---- z -> XN ----
#pragma unroll
  for (int k = 0; k < 8; k++) {
    int c = csub + 16 * k;
    float nw = n2w[c], nb = n2b[c];
    XN[(p4 + 0) * 136 + c] = bf((yv[k].x - mu2[0]) * rs2[0] * nw + nb);
    XN[(p4 + 1) * 136 + c] = bf((yv[k].y - mu2[1]) * rs2[1] * nw + nb);
    XN[(p4 + 2) * 136 + c] = bf((yv[k].z - mu2[2]) * rs2[2] * nw + nb);
    XN[(p4 + 3) * 136 + c] = bf((yv[k].w - mu2[3]) * rs2[3] * nw + nb);
  }
  __syncthreads();
  // ---- lpw GEMM -> L1 (bf16 NHWC) ----
  {
    bf8_t af[4];
#pragma unroll
    for (int kk = 0; kk < 4; kk++)
      af[kk] = *(const bf8_t*)&XN[(R0 + lr) * 136 + kk * 32 + lhi * 8];
#pragma unroll
    for (int j = 0; j < 8; j++) {
      f32x4 acc = {0.f, 0.f, 0.f, 0.f};
#pragma unroll
      for (int kk = 0; kk < 4; kk++)
        acc = mfma(af[kk], *(const bf8_t*)&Wl[(size_t)(j * 16 + lr) * 128 + kk * 32 + lhi * 8], acc);
#pragma unroll
      for (int reg = 0; reg < 4; reg++) {
        int rowp = R0 + lhi * 4 + reg;
        size_t pix = ((size_t)b * 256 + hb * 8 + (rowp >> 3)) * 256 + wb * 8 + (rowp & 7);
        L1[pix * 128 + j * 16 + lr] = bf(acc[reg]);
      }
    }
  }
}

// ---------------- K2: 3x3 depthwise conv (bf16 NHWC, 8 ch/thread) ----------------
__global__ __launch_bounds__(256)
void k_dw3(const unsigned short* __restrict__ L1, const float* __restrict__ dwW,
           const float* __restrict__ dwB, unsigned short* __restrict__ L2) {
  size_t tid = (size_t)blockIdx.x * 256 + threadIdx.x;
  int c8 = (int)(tid & 15) * 8;
  size_t pixi = tid >> 4;
  int b = (int)(pixi >> 16), rr = (int)(pixi & 65535), h = rr >> 8, w = rr & 255;
  float acc[8];
#pragma unroll
  for (int e = 0; e < 8; e++) acc[e] = dwB[c8 + e];
#pragma unroll
  for (int i = 0; i < 3; i++) {
    int h2 = h + i - 1;
    if (h2 < 0 || h2 > 255) continue;
#pragma unroll
    for (int j = 0; j < 3; j++) {
      int w2 = w + j - 1;
      if (w2 < 0 || w2 > 255) continue;
      us8 raw = *(const us8*)&L1[(((size_t)b * 256 + h2) * 256 + w2) * 128 + c8];
#pragma unroll
      for (int e = 0; e < 8; e++)
        acc[e] += fb(raw[e]) * dwW[(c8 + e) * 9 + i * 3 + j];
    }
  }
  us8 o;
#pragma unroll
  for (int e = 0; e < 8; e++) o[e] = bf(acc[e]);
  *(us8*)&L2[pixi * 128 + c8] = o;
}

// ---------------- K3: fc1 + GELU + fc2 + residual (2 barriers, 51KB LDS) ----------------
__global__ __launch_bounds__(256, 2)
void k_ffn(const unsigned short* __restrict__ L2b, const unsigned short* __restrict__ Wb,
           const float* __restrict__ fc1_b, const float* __restrict__ fc2_b,
           float* __restrict__ out) {
  __shared__ __align__(16) char smem[52224];
  unsigned short* ZT = (unsigned short*)smem;            // [64][136]
  unsigned short* HS = (unsigned short*)(smem + 17408);  // [64][136]
  unsigned short* DT = (unsigned short*)(smem + 34816);  // [128][68]

  const int t = threadIdx.x;
  const int l = t & 63, w = t >> 6;
  const int lr = l & 15, lhi = l >> 4;
  const int R0 = w * 16;

  size_t pix0 = (size_t)blockIdx.x * 64;
  const int b = (int)(pix0 >> 16), h = (int)((pix0 >> 8) & 255), w0c = (int)(pix0 & 255);

  const unsigned short* W1 = Wb + OFF_FC1;
  const unsigned short* W2 = Wb + OFF_FC2;

  for (int i = t; i < 1024; i += 256) {
    int n = i >> 4, c8 = (i & 15) * 8;
    *(us8*)&ZT[n * 136 + c8] = *(const us8*)&L2b[(pix0 + n) * 128 + c8];
  }
  __syncthreads();

  bf8_t a1[4];
#pragma unroll
  for (int kk = 0; kk < 4; kk++)
    a1[kk] = *(const bf8_t*)&ZT[(R0 + lr) * 136 + kk * 32 + lhi * 8];

  f32x4 facc[8];
#pragma unroll
  for (int j = 0; j < 8; j++) facc[j] = (f32x4){0.f, 0.f, 0.f, 0.f};

  for (int chunk = 0; chunk < 4; chunk++) {
    int hc = chunk * 128;
#pragma unroll
    for (int j = 0; j < 8; j++) {
      f32x4 ha = {0.f, 0.f, 0.f, 0.f};
#pragma unroll
      for (int kk = 0; kk < 4; kk++)
        ha = mfma(a1[kk], *(const bf8_t*)&W1[(size_t)(hc + j * 16 + lr) * 128 + kk * 32 + lhi * 8], ha);
      float bias = fc1_b[hc + j * 16 + lr];
#pragma unroll
      for (int reg = 0; reg < 4; reg++) {
        float v = ha[reg] + bias;
        HS[(R0 + lhi * 4 + reg) * 136 + j * 16 + lr] = bf(0.5f * v * (1.f + erff(v * 0.70710678118f)));
      }
    }
    bf8_t a2[4];   // own rows: wave-local, no barrier needed
#pragma unroll
    for (int kk = 0; kk < 4; kk++)
      a2[kk] = *(const bf8_t*)&HS[(R0 + lr) * 136 + kk * 32 + lhi * 8];
#pragma unroll
    for (int j = 0; j < 8; j++)
#pragma unroll
      for (int kk = 0; kk < 4; kk++)
        facc[j] = mfma(a2[kk], *(const bf8_t*)&W2[(size_t)(j * 16 + lr) * 512 + hc + kk * 32 + lhi * 8], facc[j]);
  }
#pragma unroll
  for (int j = 0; j < 8; j++) {
    int col = j * 16 + lr;
    float bias = fc2_b[col];
#pragma unroll
    for (int reg = 0; reg < 4; reg++)
      DT[col * 68 + R0 + lhi * 4 + reg] = bf(facc[j][reg] + bias);
  }
  __syncthreads();
  int p4 = (t & 15) * 4, csub = t >> 4;
#pragma unroll
  for (int k = 0; k < 8; k++) {
    int c = csub + 16 * k;
    float* po = &out[((size_t)(b * 128 + c)) * 65536 + (size_t)h * 256 + w0c + p4];
    float4 v = *(const float4*)po;
    uint2 d2 = *(const uint2*)&DT[c * 68 + p4];
    v.x += fb((unsigned short)(d2.x & 0xffff));
    v.y += fb((unsigned short)(d2.x >> 16));
    v.z += fb((unsigned short)(d2.y & 0xffff));
    v.w += fb((unsigned short)(d2.y >> 16));
    *(float4*)po = v;
  }
}

// ---------------- launch ----------------
extern "C" void kernel_launch(void* const* d_in, const int* in_sizes, int n_in,
                              void* d_out, int out_size, void* d_ws, size_t ws_size,
                              hipStream_t stream) {
  const float* x       = (const float*)d_in[0];
  const float* norm1_w = (const float*)d_in[1];
  const float* norm1_b = (const float*)d_in[2];
  const float* qkv_w   = (const float*)d_in[3];
  const float* qkv_b   = (const float*)d_in[4];
  const float* pos_b   = (const float*)d_in[5];
  const float* out_w   = (const float*)d_in[6];
  const float* out_b   = (const float*)d_in[7];
  const float* convp_w = (const float*)d_in[8];
  const float* convp_b = (const float*)d_in[9];
  const float* pw1_w   = (const float*)d_in[10];
  const float* pw1_b   = (const float*)d_in[11];
  const float* dw1_w   = (const float*)d_in[12];
  const float* dw1_b   = (const float*)d_in[13];
  const float* tok_w   = (const float*)d_in[14];
  const float* tok_b   = (const float*)d_in[15];
  const float* norm2_w = (const float*)d_in[16];
  const float* norm2_b = (const float*)d_in[17];
  const float* lpw_w   = (const float*)d_in[18];
  const float* ldw_w   = (const float*)d_in[19];
  const float* ldw_b   = (const float*)d_in[20];
  const float* fc1_w   = (const float*)d_in[21];
  const float* fc1_b   = (const float*)d_in[22];
  const float* fc2_w   = (const float*)d_in[23];
  const float* fc2_b   = (const float*)d_in[24];
  float* out = (float*)d_out;

  unsigned short* Wbf = (unsigned short*)d_ws;                                 // 532 KB arena
  unsigned short* L1  = (unsigned short*)((char*)d_ws + (1u << 20));           // 64 MB bf16
  unsigned short* L2  = (unsigned short*)((char*)d_ws + (1u << 20) + (64u << 20));

  k_prep<<<1040, 256, 0, stream>>>(qkv_w, out_w, convp_w, pw1_w, tok_w, lpw_w,
                                   fc1_w, fc2_w, pos_b, Wbf);
  k_remsa<<<4096, 256, 0, stream>>>(x, norm1_w, norm1_b, Wbf, qkv_b, out_b,
                                    convp_b, pw1_b, dw1_w, dw1_b, tok_b,
                                    norm2_w, norm2_b, out, L1);
  k_dw3<<<16384, 256, 0, stream>>>(L1, ldw_w, ldw_b, L2);
  k_ffn<<<4096, 256, 0, stream>>>(L2, Wbf, fc1_b, fc2_b, out);
}

// Round 7
// 1242.366 us; speedup vs baseline: 1.4833x; 1.3843x over previous
//
#include <hip/hip_runtime.h>
#include <hip/hip_bf16.h>
#include <cstdint>

#define DEV __device__ __forceinline__

typedef float    f32x4 __attribute__((ext_vector_type(4)));
typedef __bf16   bf8_t __attribute__((ext_vector_type(8)));
typedef unsigned short us8 __attribute__((ext_vector_type(8)));

DEV unsigned short bf(float f) {
  union { __hip_bfloat16 h; unsigned short u; } x;
  x.h = __float2bfloat16(f);
  return x.u;
}
DEV float fb(unsigned short u) {
  union { unsigned int u; float f; } x;
  x.u = (unsigned int)u << 16;
  return x.f;
}
DEV f32x4 mfma(bf8_t a, bf8_t b, f32x4 c) {
  return __builtin_amdgcn_mfma_f32_16x16x32_bf16(a, b, c, 0, 0, 0);
}

// weight arena offsets (bf16 elements) inside d_ws
#define OFF_QKV   0
#define OFF_OUT   49152
#define OFF_CONVP 65536
#define OFF_PW1   81920
#define OFF_TOK   98304
#define OFF_LPW   114688
#define OFF_FC1   131072
#define OFF_FC2   196608
#define OFF_PB    262144
#define W_TOTAL   266240

// ---- LDS weight staging (reg-staged, XOR-swizzled rows of 256B) ----
// layout: byte = row*256 + (colByte ^ ((row&7)<<4)); read row=j*16+lr matches
// write key (row&7 == lr&7) -> conflict-free ds_read_b128.
DEV void stage_w64(const unsigned short* __restrict__ Wsrc, int rsElems, int row0,
                   unsigned short* WS, int t) {
#pragma unroll
  for (int i = 0; i < 4; i++) {
    int idx = i * 256 + t;
    int o = idx >> 4, cB = (idx & 15) * 16;
    us8 v = *(const us8*)&Wsrc[(size_t)(row0 + o) * rsElems + (cB >> 1)];
    *(us8*)((char*)WS + o * 256 + (cB ^ ((o & 7) << 4))) = v;
  }
}
DEV void stage_w128(const unsigned short* __restrict__ Wsrc, int rsElems,
                    unsigned short* WS, int t) {
#pragma unroll
  for (int i = 0; i < 8; i++) {
    int idx = i * 256 + t;
    int o = idx >> 4, cB = (idx & 15) * 16;
    us8 v = *(const us8*)&Wsrc[(size_t)o * rsElems + (cB >> 1)];
    *(us8*)((char*)WS + o * 256 + (cB ^ ((o & 7) << 4))) = v;
  }
}
DEV bf8_t wfrag(const unsigned short* WS, int row, int kk, int lhi, int lr) {
  return *(const bf8_t*)((const char*)WS + row * 256 +
                         ((kk * 64 + lhi * 16) ^ ((lr & 7) << 4)));
}

// ---------------- K0: convert weights (+pos_bias) to bf16 ----------------
__global__ __launch_bounds__(256)
void k_prep(const float* __restrict__ qkv_w, const float* __restrict__ out_w,
            const float* __restrict__ convp_w, const float* __restrict__ pw1_w,
            const float* __restrict__ tok_w, const float* __restrict__ lpw_w,
            const float* __restrict__ fc1_w, const float* __restrict__ fc2_w,
            const float* __restrict__ pos_b, unsigned short* __restrict__ Wb) {
  int i = blockIdx.x * 256 + threadIdx.x;
  float v;
  if      (i < OFF_OUT)   v = qkv_w[i - OFF_QKV];
  else if (i < OFF_CONVP) v = out_w[i - OFF_OUT];
  else if (i < OFF_PW1)   v = convp_w[i - OFF_CONVP];
  else if (i < OFF_TOK)   v = pw1_w[i - OFF_PW1];
  else if (i < OFF_LPW)   v = tok_w[i - OFF_TOK];
  else if (i < OFF_FC1)   v = lpw_w[i - OFF_LPW];
  else if (i < OFF_FC2)   v = fc1_w[i - OFF_FC1];
  else if (i < OFF_PB)    v = fc2_w[i - OFF_FC2];
  else                    v = pos_b[i - OFF_PB];
  Wb[i] = bf(v);
}

// ---------------- K1: fused remsa (one 8x8 window per block) ----------------
__global__ __launch_bounds__(256, 2)
void k_remsa(const float* __restrict__ x, const float* __restrict__ n1w,
             const float* __restrict__ n1b, const unsigned short* __restrict__ Wb,
             const float* __restrict__ qkv_b, const float* __restrict__ out_b,
             const float* __restrict__ convp_b, const float* __restrict__ pw1_b,
             const float* __restrict__ dw1_w, const float* __restrict__ dw1_b,
             const float* __restrict__ tok_b, const float* __restrict__ n2w,
             const float* __restrict__ n2b, float* __restrict__ yout,
             unsigned short* __restrict__ L1) {
  __shared__ __align__(16) char smem[52224];
  unsigned short* XN = (unsigned short*)smem;            // [64][136] xn -> t2 -> z
  unsigned short* AO = (unsigned short*)(smem + 17408);  // [64][136] ao -> t1 -> t3; ARED overlay
  unsigned short* S16 = (unsigned short*)(smem + 34816); // QK / weight-staging / DT / SRED
  float* SRED = (float*)(smem + 34816);
  float* ARED = (float*)(smem + 17408);

  const int t = threadIdx.x;
  const int l = t & 63, w = t >> 6;
  const int lr = l & 15, lhi = l >> 4;
  const int R0 = w * 16;
  const int p4 = (t & 15) * 4;
  const int csub = t >> 4;
  const int pr = p4 >> 3, ps = p4 & 7;

  const int win = ((blockIdx.x & 7) << 9) | (blockIdx.x >> 3);  // XCD swizzle
  const int b = win >> 10, rem = win & 1023, hb = rem >> 5, wb = rem & 31;
  const float* xb = x + (size_t)b * 8388608 + (size_t)(hb * 8) * 256 + wb * 8;
  float*       yb = yout + (size_t)b * 8388608 + (size_t)(hb * 8) * 256 + wb * 8;

  const unsigned short* Wq = Wb + OFF_QKV;
  const unsigned short* Wo = Wb + OFF_OUT;
  const unsigned short* Wc = Wb + OFF_CONVP;
  const unsigned short* Wp = Wb + OFF_PW1;
  const unsigned short* Wt = Wb + OFF_TOK;
  const unsigned short* Wl = Wb + OFF_LPW;
  const unsigned short* PB = Wb + OFF_PB;

  // ---- x in regs (c-major), LN1 ----
  float4 xv[8];
#pragma unroll
  for (int k = 0; k < 8; k++)
    xv[k] = *(const float4*)&xb[(size_t)(csub + 16 * k) * 65536 + pr * 256 + ps];
  float s1[4] = {0.f, 0.f, 0.f, 0.f}, q1[4] = {0.f, 0.f, 0.f, 0.f};
#pragma unroll
  for (int k = 0; k < 8; k++) {
    s1[0] += xv[k].x; q1[0] += xv[k].x * xv[k].x;
    s1[1] += xv[k].y; q1[1] += xv[k].y * xv[k].y;
    s1[2] += xv[k].z; q1[2] += xv[k].z * xv[k].z;
    s1[3] += xv[k].w; q1[3] += xv[k].w * xv[k].w;
  }
#pragma unroll
  for (int m = 16; m <= 32; m <<= 1)
#pragma unroll
    for (int i = 0; i < 4; i++) {
      s1[i] += __shfl_xor(s1[i], m, 64);
      q1[i] += __shfl_xor(q1[i], m, 64);
    }
  if (lhi == 0)
#pragma unroll
    for (int i = 0; i < 4; i++) {
      SRED[w * 128 + (p4 + i) * 2]     = s1[i];
      SRED[w * 128 + (p4 + i) * 2 + 1] = q1[i];
    }
  __syncthreads();
  float mu1[4], rs1[4];
#pragma unroll
  for (int i = 0; i < 4; i++) {
    float ss = 0.f, qq = 0.f;
#pragma unroll
    for (int w2 = 0; w2 < 4; w2++) {
      ss += SRED[w2 * 128 + (p4 + i) * 2];
      qq += SRED[w2 * 128 + (p4 + i) * 2 + 1];
    }
    mu1[i] = ss * 0.0078125f;
    rs1[i] = rsqrtf(qq * 0.0078125f - mu1[i] * mu1[i] + 1e-5f);
  }
#pragma unroll
  for (int k = 0; k < 8; k++) {
    int c = csub + 16 * k;
    float nw = n1w[c], nb = n1b[c];
    XN[(p4 + 0) * 136 + c] = bf((xv[k].x - mu1[0]) * rs1[0] * nw + nb);
    XN[(p4 + 1) * 136 + c] = bf((xv[k].y - mu1[1]) * rs1[1] * nw + nb);
    XN[(p4 + 2) * 136 + c] = bf((xv[k].z - mu1[2]) * rs1[2] * nw + nb);
    XN[(p4 + 3) * 136 + c] = bf((xv[k].w - mu1[3]) * rs1[3] * nw + nb);
  }
  __syncthreads();

  // ---- qkv GEMM + attention (global weight frags; S16 holds QK tile) ----
  for (int tt = 0; tt < 4; tt++) {
    {
      bf8_t af[4];
#pragma unroll
      for (int kk = 0; kk < 4; kk++)
        af[kk] = *(const bf8_t*)&XN[(tt * 16 + lr) * 136 + kk * 32 + lhi * 8];
#pragma unroll
      for (int j = 0; j < 6; j++) {
        int o0 = w * 96 + j * 16;
        f32x4 acc = {0.f, 0.f, 0.f, 0.f};
#pragma unroll
        for (int kk = 0; kk < 4; kk++)
          acc = mfma(af[kk], *(const bf8_t*)&Wq[(size_t)(o0 + lr) * 128 + kk * 32 + lhi * 8], acc);
        float bias = qkv_b[o0 + lr];
#pragma unroll
        for (int reg = 0; reg < 4; reg++)
          S16[(lhi * 4 + reg) * 392 + o0 + lr] = bf(acc[reg] + bias);
      }
    }
    __syncthreads();
    {
      int half = t >> 7, lt = (t >> 3) & 15, hh = t & 7, n = tt * 16 + lt;
      const unsigned short* row = &S16[lt * 392];
      float qv[16];
      us8 u0 = *(const us8*)&row[hh * 48], u1 = *(const us8*)&row[hh * 48 + 8];
#pragma unroll
      for (int d = 0; d < 8; d++) { qv[d] = fb(u0[d]); qv[8 + d] = fb(u1[d]); }
      us8 pb = *(const us8*)&PB[n * 64 + hh * 8];
      float sc[8], mx = -1e30f;
#pragma unroll
      for (int g = 0; g < 8; g++) {
        us8 k0 = *(const us8*)&row[g * 48 + 16], k1 = *(const us8*)&row[g * 48 + 24];
        float s = 0.f;
#pragma unroll
        for (int d = 0; d < 8; d++) s += qv[d] * fb(k0[d]) + qv[8 + d] * fb(k1[d]);
        s = s * 0.25f + fb(pb[g]);
        sc[g] = s; mx = fmaxf(mx, s);
      }
      float den = 0.f;
#pragma unroll
      for (int g = 0; g < 8; g++) { sc[g] = __expf(sc[g] - mx); den += sc[g]; }
      float inv = 1.f / den;
      float ov[8];
#pragma unroll
      for (int d = 0; d < 8; d++) ov[d] = 0.f;
#pragma unroll
      for (int g = 0; g < 8; g++) {
        us8 vv = *(const us8*)&row[g * 48 + 32 + half * 8];
        float sg = sc[g];
#pragma unroll
        for (int d = 0; d < 8; d++) ov[d] += sg * fb(vv[d]);
      }
      us8 op;
#pragma unroll
      for (int d = 0; d < 8; d++) op[d] = bf(ov[d] * inv);
      *(us8*)&AO[n * 136 + hh * 16 + half * 8] = op;
    }
    __syncthreads();
  }

  // ================= staged post-attention GEMMs =================
  f32x4 acc1[8];
#pragma unroll
  for (int j = 0; j < 8; j++) acc1[j] = (f32x4){0.f, 0.f, 0.f, 0.f};

  // ---- OUT-proj (AO -> acc1) ----
  {
    bf8_t af[4];
#pragma unroll
    for (int kk = 0; kk < 4; kk++)
      af[kk] = *(const bf8_t*)&AO[(R0 + lr) * 136 + kk * 32 + lhi * 8];
    stage_w64(Wo, 128, 0, S16, t);
    __syncthreads();
#pragma unroll
    for (int jj = 0; jj < 4; jj++)
#pragma unroll
      for (int kk = 0; kk < 4; kk++)
        acc1[jj] = mfma(af[kk], wfrag(S16, jj * 16 + lr, kk, lhi, lr), acc1[jj]);
    __syncthreads();
    stage_w64(Wo, 128, 64, S16, t);
    __syncthreads();
#pragma unroll
    for (int jj = 0; jj < 4; jj++)
#pragma unroll
      for (int kk = 0; kk < 4; kk++)
        acc1[4 + jj] = mfma(af[kk], wfrag(S16, jj * 16 + lr, kk, lhi, lr), acc1[4 + jj]);
    __syncthreads();
  }
  // ---- CONVP (XN -> t1 in AO own rows) ----
  {
    f32x4 acc2[8];
#pragma unroll
    for (int j = 0; j < 8; j++) acc2[j] = (f32x4){0.f, 0.f, 0.f, 0.f};
    bf8_t af[4];
#pragma unroll
    for (int kk = 0; kk < 4; kk++)
      af[kk] = *(const bf8_t*)&XN[(R0 + lr) * 136 + kk * 32 + lhi * 8];
    stage_w64(Wc, 128, 0, S16, t);
    __syncthreads();
#pragma unroll
    for (int jj = 0; jj < 4; jj++)
#pragma unroll
      for (int kk = 0; kk < 4; kk++)
        acc2[jj] = mfma(af[kk], wfrag(S16, jj * 16 + lr, kk, lhi, lr), acc2[jj]);
    __syncthreads();
    stage_w64(Wc, 128, 64, S16, t);
    __syncthreads();
#pragma unroll
    for (int jj = 0; jj < 4; jj++)
#pragma unroll
      for (int kk = 0; kk < 4; kk++)
        acc2[4 + jj] = mfma(af[kk], wfrag(S16, jj * 16 + lr, kk, lhi, lr), acc2[4 + jj]);
#pragma unroll
    for (int j = 0; j < 8; j++) {
      float bias = convp_b[j * 16 + lr];
#pragma unroll
      for (int reg = 0; reg < 4; reg++)
        AO[(R0 + lhi * 4 + reg) * 136 + j * 16 + lr] = bf(acc2[j][reg] + bias);
    }
    __syncthreads();
  }
  // ---- PW1 (t1 -> t2 in XN own rows) ----
  {
    f32x4 acc2[8];
#pragma unroll
    for (int j = 0; j < 8; j++) acc2[j] = (f32x4){0.f, 0.f, 0.f, 0.f};
    bf8_t af[4];
#pragma unroll
    for (int kk = 0; kk < 4; kk++)
      af[kk] = *(const bf8_t*)&AO[(R0 + lr) * 136 + kk * 32 + lhi * 8];
    stage_w64(Wp, 128, 0, S16, t);
    __syncthreads();
#pragma unroll
    for (int jj = 0; jj < 4; jj++)
#pragma unroll
      for (int kk = 0; kk < 4; kk++)
        acc2[jj] = mfma(af[kk], wfrag(S16, jj * 16 + lr, kk, lhi, lr), acc2[jj]);
    __syncthreads();
    stage_w64(Wp, 128, 64, S16, t);
    __syncthreads();
#pragma unroll
    for (int jj = 0; jj < 4; jj++)
#pragma unroll
      for (int kk = 0; kk < 4; kk++)
        acc2[4 + jj] = mfma(af[kk], wfrag(S16, jj * 16 + lr, kk, lhi, lr), acc2[4 + jj]);
#pragma unroll
    for (int j = 0; j < 8; j++) {
      float bias = pw1_b[j * 16 + lr];
#pragma unroll
      for (int reg = 0; reg < 4; reg++)
        XN[(R0 + lhi * 4 + reg) * 136 + j * 16 + lr] = bf(acc2[j][reg] + bias);
    }
    __syncthreads();   // t2 visible (dw reads neighbor rows)
  }
  // ---- DW token conv (t2 -> t3 in AO own rows) ----
  {
    float dwc[2][4];
#pragma unroll
    for (int h2 = 0; h2 < 2; h2++) {
      int c = l + 64 * h2;
      dwc[h2][0] = dw1_w[c * 3]; dwc[h2][1] = dw1_w[c * 3 + 1];
      dwc[h2][2] = dw1_w[c * 3 + 2]; dwc[h2][3] = dw1_b[c];
    }
#pragma unroll
    for (int k2 = 0; k2 < 32; k2++) {
      int n = R0 + (k2 >> 1), h2 = k2 & 1, c = l + 64 * h2;
      float v = dwc[h2][3] + dwc[h2][1] * fb(XN[n * 136 + c]);
      if (n > 0)  v += dwc[h2][0] * fb(XN[(n - 1) * 136 + c]);
      if (n < 63) v += dwc[h2][2] * fb(XN[(n + 1) * 136 + c]);
      AO[n * 136 + c] = bf(v);
    }
  }
  // ---- TOK (t3 -> acc1) ----
  {
    bf8_t af[4];
#pragma unroll
    for (int kk = 0; kk < 4; kk++)
      af[kk] = *(const bf8_t*)&AO[(R0 + lr) * 136 + kk * 32 + lhi * 8];
    stage_w64(Wt, 128, 0, S16, t);
    __syncthreads();
#pragma unroll
    for (int jj = 0; jj < 4; jj++)
#pragma unroll
      for (int kk = 0; kk < 4; kk++)
        acc1[jj] = mfma(af[kk], wfrag(S16, jj * 16 + lr, kk, lhi, lr), acc1[jj]);
    __syncthreads();
    stage_w64(Wt, 128, 64, S16, t);
    __syncthreads();
#pragma unroll
    for (int jj = 0; jj < 4; jj++)
#pragma unroll
      for (int kk = 0; kk < 4; kk++)
        acc1[4 + jj] = mfma(af[kk], wfrag(S16, jj * 16 + lr, kk, lhi, lr), acc1[4 + jj]);
    __syncthreads();   // S reads done -> DT may overwrite
  }
  // ---- Delta transpose into S ----
  unsigned short* DT = S16;   // [128][68]
#pragma unroll
  for (int j = 0; j < 8; j++) {
    int col = j * 16 + lr;
    float bsum = out_b[col] + tok_b[col];
#pragma unroll
    for (int reg = 0; reg < 4; reg++)
      DT[col * 68 + R0 + lhi * 4 + reg] = bf(acc1[j][reg] + bsum);
  }
  __syncthreads();

  // ---- epilogue: y = x + Delta; yout; LN2 ----
  float4 yv[8];
  float s2[4] = {0.f, 0.f, 0.f, 0.f}, q2[4] = {0.f, 0.f, 0.f, 0.f};
#pragma unroll
  for (int k = 0; k < 8; k++) {
    int c = csub + 16 * k;
    uint2 d2 = *(const uint2*)&DT[c * 68 + p4];
    float4 v;
    v.x = xv[k].x + fb((unsigned short)(d2.x & 0xffff));
    v.y = xv[k].y + fb((unsigned short)(d2.x >> 16));
    v.z = xv[k].z + fb((unsigned short)(d2.y & 0xffff));
    v.w = xv[k].w + fb((unsigned short)(d2.y >> 16));
    yv[k] = v;
    *(float4*)&yb[(size_t)c * 65536 + pr * 256 + ps] = v;
    s2[0] += v.x; q2[0] += v.x * v.x;
    s2[1] += v.y; q2[1] += v.y * v.y;
    s2[2] += v.z; q2[2] += v.z * v.z;
    s2[3] += v.w; q2[3] += v.w * v.w;
  }
#pragma unroll
  for (int m = 16; m <= 32; m <<= 1)
#pragma unroll
    for (int i = 0; i < 4; i++) {
      s2[i] += __shfl_xor(s2[i], m, 64);
      q2[i] += __shfl_xor(q2[i], m, 64);
    }
  if (lhi == 0)
#pragma unroll
    for (int i = 0; i < 4; i++) {
      ARED[w * 128 + (p4 + i) * 2]     = s2[i];
      ARED[w * 128 + (p4 + i) * 2 + 1] = q2[i];
    }
  __syncthreads();   // all DT reads done too
  stage_w64(Wl, 128, 0, S16, t);   // overwrite DT with lpw half0
  float mu2[4], rs2[4];
#pragma unroll
  for (int i = 0; i < 4; i++) {
    float ss = 0.f, qq = 0.f;
#pragma unroll
    for (int w2 = 0; w2 < 4; w2++) {
      ss += ARED[w2 * 128 + (p4 + i) * 2];
      qq += ARED[w2 * 128 + (p4 + i) * 2 + 1];
    }
    mu2[i] = ss * 0.0078125f;
    rs2[i] = rsqrtf(qq * 0.0078125f - mu2[i] * mu2[i] + 1e-5f);
  }
#pragma unroll
  for (int k = 0; k < 8; k++) {
    int c = csub + 16 * k;
    float nw = n2w[c], nb = n2b[c];
    XN[(p4 + 0) * 136 + c] = bf((yv[k].x - mu2[0]) * rs2[0] * nw + nb);
    XN[(p4 + 1) * 136 + c] = bf((yv[k].y - mu2[1]) * rs2[1] * nw + nb);
    XN[(p4 + 2) * 136 + c] = bf((yv[k].z - mu2[2]) * rs2[2] * nw + nb);
    XN[(p4 + 3) * 136 + c] = bf((yv[k].w - mu2[3]) * rs2[3] * nw + nb);
  }
  __syncthreads();   // z + lpw half0 staged
  // ---- LPW (z -> L1 bf16 NHWC) ----
  {
    bf8_t af[4];
#pragma unroll
    for (int kk = 0; kk < 4; kk++)
      af[kk] = *(const bf8_t*)&XN[(R0 + lr) * 136 + kk * 32 + lhi * 8];
    f32x4 la[8];
#pragma unroll
    for (int j = 0; j < 8; j++) la[j] = (f32x4){0.f, 0.f, 0.f, 0.f};
#pragma unroll
    for (int jj = 0; jj < 4; jj++)
#pragma unroll
      for (int kk = 0; kk < 4; kk++)
        la[jj] = mfma(af[kk], wfrag(S16, jj * 16 + lr, kk, lhi, lr), la[jj]);
    __syncthreads();
    stage_w64(Wl, 128, 64, S16, t);
    __syncthreads();
#pragma unroll
    for (int jj = 0; jj < 4; jj++)
#pragma unroll
      for (int kk = 0; kk < 4; kk++)
        la[4 + jj] = mfma(af[kk], wfrag(S16, jj * 16 + lr, kk, lhi, lr), la[4 + jj]);
#pragma unroll
    for (int j = 0; j < 8; j++)
#pragma unroll
      for (int reg = 0; reg < 4; reg++) {
        int rowp = R0 + lhi * 4 + reg;
        size_t pix = ((size_t)b * 256 + hb * 8 + (rowp >> 3)) * 256 + wb * 8 + (rowp & 7);
        L1[pix * 128 + j * 16 + lr] = bf(la[j][reg]);
      }
  }
}

// ---------------- K2: 3x3 depthwise conv (bf16 NHWC, 8 ch/thread) ----------------
__global__ __launch_bounds__(256)
void k_dw3(const unsigned short* __restrict__ L1, const float* __restrict__ dwW,
           const float* __restrict__ dwB, unsigned short* __restrict__ L2) {
  size_t tid = (size_t)blockIdx.x * 256 + threadIdx.x;
  int c8 = (int)(tid & 15) * 8;
  size_t pixi = tid >> 4;
  int b = (int)(pixi >> 16), rr = (int)(pixi & 65535), h = rr >> 8, w = rr & 255;
  float acc[8];
#pragma unroll
  for (int e = 0; e < 8; e++) acc[e] = dwB[c8 + e];
#pragma unroll
  for (int i = 0; i < 3; i++) {
    int h2 = h + i - 1;
    if (h2 < 0 || h2 > 255) continue;
#pragma unroll
    for (int j = 0; j < 3; j++) {
      int w2 = w + j - 1;
      if (w2 < 0 || w2 > 255) continue;
      us8 raw = *(const us8*)&L1[(((size_t)b * 256 + h2) * 256 + w2) * 128 + c8];
#pragma unroll
      for (int e = 0; e < 8; e++)
        acc[e] += fb(raw[e]) * dwW[(c8 + e) * 9 + i * 3 + j];
    }
  }
  us8 o;
#pragma unroll
  for (int e = 0; e < 8; e++) o[e] = bf(acc[e]);
  *(us8*)&L2[pixi * 128 + c8] = o;
}

// ---------------- K3: LDS-staged FFN (fc1+GELU+fc2+residual) ----------------
// WS 32KB staged weights (XOR-swizzled) + HS 17KB per-wave hidden = 50KB LDS.
// fc2 uses operand-swapped mfma -> D[channel][token] -> direct coalesced RMW.
__global__ __launch_bounds__(256, 2)
void k_ffn(const unsigned short* __restrict__ L2b, const unsigned short* __restrict__ Wb,
           const float* __restrict__ fc1_b, const float* __restrict__ fc2_b,
           float* __restrict__ out) {
  __shared__ __align__(16) unsigned short WS[16384];     // 32KB staging
  __shared__ __align__(16) unsigned short HS[4 * 16 * 136];  // per-wave hidden

  const int t = threadIdx.x;
  const int l = t & 63, w = t >> 6;
  const int lr = l & 15, lhi = l >> 4;
  const int R0 = w * 16;
  unsigned short* HSw = HS + w * 16 * 136;

  size_t pix0 = (size_t)blockIdx.x * 64;
  const int b = (int)(pix0 >> 16), hpix = (int)((pix0 >> 8) & 255), w0c = (int)(pix0 & 255);

  const unsigned short* W1 = Wb + OFF_FC1;
  const unsigned short* W2 = Wb + OFF_FC2;

  // a1 fragments straight from global (once)
  bf8_t a1[4];
#pragma unroll
  for (int kk = 0; kk < 4; kk++)
    a1[kk] = *(const bf8_t*)&L2b[(pix0 + R0 + lr) * 128 + kk * 32 + lhi * 8];

  f32x4 facc[8];
#pragma unroll
  for (int j = 0; j < 8; j++) facc[j] = (f32x4){0.f, 0.f, 0.f, 0.f};

  stage_w128(W1, 128, WS, t);   // chunk 0 fc1 weights
  for (int chunk = 0; chunk < 4; chunk++) {
    int hc = chunk * 128;
    __syncthreads();            // staging visible
    // fc1 + GELU -> HS (wave-local)
#pragma unroll
    for (int j = 0; j < 8; j++) {
      f32x4 ha = {0.f, 0.f, 0.f, 0.f};
#pragma unroll
      for (int kk = 0; kk < 4; kk++)
        ha = mfma(a1[kk], wfrag(WS, j * 16 + lr, kk, lhi, lr), ha);
      float bias = fc1_b[hc + j * 16 + lr];
#pragma unroll
      for (int reg = 0; reg < 4; reg++) {
        float v = ha[reg] + bias;
        HSw[(lhi * 4 + reg) * 136 + j * 16 + lr] = bf(0.5f * v * (1.f + erff(v * 0.70710678118f)));
      }
    }
    __syncthreads();            // WS reads done
    stage_w128(W2 + hc, 512, WS, t);   // fc2 chunk: rows=o(128), cols=h-slice
    __syncthreads();            // staged
    bf8_t a2[4];
#pragma unroll
    for (int kk = 0; kk < 4; kk++)
      a2[kk] = *(const bf8_t*)&HSw[lr * 136 + kk * 32 + lhi * 8];
#pragma unroll
    for (int j = 0; j < 8; j++)
#pragma unroll
      for (int kk = 0; kk < 4; kk++)
        facc[j] = mfma(wfrag(WS, j * 16 + lr, kk, lhi, lr), a2[kk], facc[j]);
    if (chunk < 3) {
      __syncthreads();          // WS reads done
      stage_w128(W1 + (hc + 128) * 128, 128, WS, t);
    }
  }
  // epilogue: channel c = j*16 + lhi*4 + reg, token = pix0 + R0 + lr
#pragma unroll
  for (int j = 0; j < 8; j++)
#pragma unroll
    for (int reg = 0; reg < 4; reg++) {
      int c = j * 16 + lhi * 4 + reg;
      float* po = &out[((size_t)(b * 128 + c)) * 65536 + (size_t)hpix * 256 + w0c + R0 + lr];
      *po += facc[j][reg] + fc2_b[c];
    }
}

// ---------------- launch ----------------
extern "C" void kernel_launch(void* const* d_in, const int* in_sizes, int n_in,
                              void* d_out, int out_size, void* d_ws, size_t ws_size,
                              hipStream_t stream) {
  const float* x       = (const float*)d_in[0];
  const float* norm1_w = (const float*)d_in[1];
  const float* norm1_b = (const float*)d_in[2];
  const float* qkv_w   = (const float*)d_in[3];
  const float* qkv_b   = (const float*)d_in[4];
  const float* pos_b   = (const float*)d_in[5];
  const float* out_w   = (const float*)d_in[6];
  const float* out_b   = (const float*)d_in[7];
  const float* convp_w = (const float*)d_in[8];
  const float* convp_b = (const float*)d_in[9];
  const float* pw1_w   = (const float*)d_in[10];
  const float* pw1_b   = (const float*)d_in[11];
  const float* dw1_w   = (const float*)d_in[12];
  const float* dw1_b   = (const float*)d_in[13];
  const float* tok_w   = (const float*)d_in[14];
  const float* tok_b   = (const float*)d_in[15];
  const float* norm2_w = (const float*)d_in[16];
  const float* norm2_b = (const float*)d_in[17];
  const float* lpw_w   = (const float*)d_in[18];
  const float* ldw_w   = (const float*)d_in[19];
  const float* ldw_b   = (const float*)d_in[20];
  const float* fc1_w   = (const float*)d_in[21];
  const float* fc1_b   = (const float*)d_in[22];
  const float* fc2_w   = (const float*)d_in[23];
  const float* fc2_b   = (const float*)d_in[24];
  float* out = (float*)d_out;

  unsigned short* Wbf = (unsigned short*)d_ws;
  unsigned short* L1  = (unsigned short*)((char*)d_ws + (1u << 20));
  unsigned short* L2  = (unsigned short*)((char*)d_ws + (1u << 20) + (64u << 20));

  k_prep<<<1040, 256, 0, stream>>>(qkv_w, out_w, convp_w, pw1_w, tok_w, lpw_w,
                                   fc1_w, fc2_w, pos_b, Wbf);
  k_remsa<<<4096, 256, 0, stream>>>(x, norm1_w, norm1_b, Wbf, qkv_b, out_b,
                                    convp_b, pw1_b, dw1_w, dw1_b, tok_b,
                                    norm2_w, norm2_b, out, L1);
  k_dw3<<<16384, 256, 0, stream>>>(L1, ldw_w, ldw_b, L2);
  k_ffn<<<4096, 256, 0, stream>>>(L2, Wbf, fc1_b, fc2_b, out);
}